// Round 5
// baseline (898.623 us; speedup 1.0000x reference)
//
#include <hip/hip_runtime.h>

// ---------------- dtype helpers ----------------
__device__ __forceinline__ float b2f(unsigned short u) {
  return __uint_as_float(((unsigned)u) << 16);
}
__device__ __forceinline__ unsigned short f2b(float f) {
  unsigned u = __float_as_uint(f);
  return (unsigned short)((u + 0x7FFFu + ((u >> 16) & 1u)) >> 16);
}
// load element i of a tensor that is bf16 (isb=1) or fp32 (isb=0)
__device__ __forceinline__ float gload(const void* p, int i, int isb) {
  return isb ? b2f(((const unsigned short*)p)[i]) : ((const float*)p)[i];
}
// monotone bijection float -> uint32 (order-preserving incl. negatives)
__device__ __forceinline__ unsigned tokey(float f) {
  unsigned u = __float_as_uint(f);
  return u ^ (unsigned)(((int)u >> 31) | 0x80000000u);
}

// ---------------- dtype detector ----------------
// Evidence from rounds 1-4: this dataset is fp32 (flag=0 path runs).
// Keep the detector for safety; it is cheap and graph-capture safe.
__global__ void k_detect(const void* x, int* flag) {
  int tid = threadIdx.x;  // 1 wave
  unsigned short u = ((const unsigned short*)x)[2 * tid];
  int e = (u >> 7) & 0xFF;
  bool sane = (e >= 100 && e <= 140);
  unsigned long long m = __ballot(sane);
  if (tid == 0) *flag = (__popcll(m) >= 40) ? 1 : 0;
}

// ---------------- k_prep: Wt[i][u] = fc1_w[u][i] * (mask<0.5), bf16-pair packed ----------------
// NOTE: for fp32 datasets this packs masked weights to bf16 pairs -- that would
// LOSE precision for the fc1 matmul. For fp32 we must keep full f32 weights.
// So k_prep now writes TWO layouts: bf16-pair (isb=1 datasets) and full f32
// transposed (isb=0 datasets). k_fc picks per flag.
__global__ __launch_bounds__(256) void k_prep(const void* __restrict__ fc1w,
                                              const void* __restrict__ mraw,
                                              unsigned* __restrict__ Wt2,
                                              float* __restrict__ WtF,
                                              const int* __restrict__ flag) {
  __shared__ float tile[64][65];
  const int isb = *flag;
  const int i0 = blockIdx.x * 64;  // K index (9216)
  const int u0 = blockIdx.y * 64;  // unit index (1024)
  const int tx = threadIdx.x & 63, ty = threadIdx.x >> 6;
  for (int uu = ty; uu < 64; uu += 4) {
    int gi = (u0 + uu) * 9216 + i0 + tx;
    float wv = gload(fc1w, gi, isb);
    float mv = gload(mraw, gi, isb);
    tile[uu][tx] = (mv < 0.5f) ? wv : 0.0f;
  }
  __syncthreads();
  if (isb) {
    const int jx = threadIdx.x & 31, jy = threadIdx.x >> 5;
    for (int ii = jy; ii < 64; ii += 8) {
      unsigned lo = f2b(tile[2 * jx][ii]);
      unsigned hi = f2b(tile[2 * jx + 1][ii]);
      Wt2[(i0 + ii) * 512 + (u0 >> 1) + jx] = lo | (hi << 16);
    }
  } else {
    for (int ii = ty; ii < 64; ii += 4)
      WtF[(i0 + ii) * 1024 + u0 + tx] = tile[tx][ii];
  }
}

// ---------------- k_conv: f32 conv5x5, Eigen patch order (kh fastest), bias, maxpool2, kwinners ----------------
__global__ __launch_bounds__(256) void k_conv(const void* __restrict__ x,
                                              const void* __restrict__ c1w_g,
                                              const void* __restrict__ c1b_g,
                                              const void* __restrict__ duty_g,
                                              float* __restrict__ wval,
                                              int* __restrict__ widx,
                                              int* __restrict__ wcnt,
                                              const int* __restrict__ flag) {
  __shared__ __align__(16) float img[784];
  __shared__ float cw[1600];
  __shared__ float cb[64], bcs[64];
  __shared__ __align__(16) float pooled[9216];
  __shared__ unsigned hist[256];
  __shared__ unsigned selb, selk;
  __shared__ int cnt;
  const int tid = threadIdx.x;
  const int b = blockIdx.x;
  const int isb = *flag;

  for (int i = tid; i < 784; i += 256) img[i] = gload(x, b * 784 + i, isb);
  for (int i = tid; i < 1600; i += 256) cw[i] = gload(c1w_g, i, isb);
  if (tid < 64) {
    cb[tid] = gload(c1b_g, tid, isb);
    // boost = f32(exp(f32(400/9216) - duty)); libm-quality exp == (f32)exp(f64)
    float arg = (float)(400.0 / 9216.0) - gload(duty_g, tid, isb);
    bcs[tid] = (float)exp((double)arg);
  }
  if (tid == 0) cnt = 0;
  __syncthreads();

  // 1536 tasks = 64 ch x 12 pooled rows x 2 halves; 6 per thread.
  // All 6 needed image rows (16-col window) in registers so the 25-tap sum is a
  // SINGLE sequential fmaf chain in k = kw*5 + kh order (kh fastest -- Eigen
  // column-major patch linearization), matching the reference's f32 conv.
  for (int s = 0; s < 6; ++s) {
    int t = tid + (s << 8);
    int c = t / 24;
    int sub = t - c * 24;
    int ph = sub >> 1;
    int half = sub & 1;
    float w[25];
#pragma unroll
    for (int i = 0; i < 25; ++i) w[i] = cw[c * 25 + i];
    float R[6][16];
#pragma unroll
    for (int rr = 0; rr < 6; ++rr) {
      int row = 2 * ph + rr;
#pragma unroll
      for (int q = 0; q < 4; ++q)
        ((float4*)&R[rr][0])[q] = ((const float4*)img)[row * 7 + half * 3 + q];
    }
    float a0[12], a1[12];
#pragma unroll
    for (int j = 0; j < 12; ++j) { a0[j] = 0.f; a1[j] = 0.f; }
#pragma unroll
    for (int kj = 0; kj < 5; ++kj) {       // kw OUTER
#pragma unroll
      for (int kr = 0; kr < 5; ++kr) {     // kh INNER (fastest)
        float wk = w[kr * 5 + kj];
#pragma unroll
        for (int j = 0; j < 12; ++j) {
          a0[j] = fmaf(R[kr][j + kj], wk, a0[j]);
          a1[j] = fmaf(R[kr + 1][j + kj], wk, a1[j]);
        }
      }
    }
    float bias = cb[c];
    int obase = c * 144 + ph * 12 + half * 6;
    // bias-then-pool == pool-then-bias bitwise (fl(a+b) monotone in a)
#pragma unroll
    for (int q = 0; q < 6; ++q) {
      float m = fmaxf(fmaxf(a0[2 * q], a0[2 * q + 1]),
                      fmaxf(a1[2 * q], a1[2 * q + 1]));
      pooled[obase + q] = m + bias;
    }
  }
  __syncthreads();

  // radix-select the 400th-largest f32 boosted key (exact top_k threshold)
  unsigned kfix = 0;
  int kk = 400;
  for (int pass = 3; pass >= 0; --pass) {
    const int shift = pass * 8;
    const unsigned himask = (pass == 3) ? 0u : (0xFFFFFFFFu << (shift + 8));
    hist[tid] = 0;
    __syncthreads();
    for (int e = 0; e < 9; ++e) {
      float4 pv = ((float4*)pooled)[tid * 9 + e];
#pragma unroll
      for (int q = 0; q < 4; ++q) {
        int o = tid * 36 + e * 4 + q;
        unsigned key = tokey(((float*)&pv)[q] * bcs[o / 144]);
        if (((key ^ kfix) & himask) == 0)
          atomicAdd(&hist[(key >> shift) & 255u], 1u);
      }
    }
    __syncthreads();
    unsigned v = hist[tid];
    for (int offs = 1; offs < 256; offs <<= 1) {
      unsigned other = (tid + offs < 256) ? hist[tid + offs] : 0u;
      __syncthreads();
      v += other;
      hist[tid] = v;
      __syncthreads();
    }
    unsigned snext = (tid < 255) ? hist[tid + 1] : 0u;
    if (v >= (unsigned)kk && snext < (unsigned)kk) {
      selb = (unsigned)tid;
      selk = (unsigned)(kk - (int)snext);
    }
    __syncthreads();
    kfix |= selb << shift;
    kk = (int)selk;
    __syncthreads();
  }

  // keep ALL with key >= kfix (== boosted >= thr bitwise, ties kept like ref)
  for (int e = 0; e < 36; ++e) {
    int o = tid * 36 + e;
    float pv = pooled[o];
    unsigned key = tokey(pv * bcs[o / 144]);
    if (key >= kfix) {
      int pos = atomicAdd(&cnt, 1);
      if (pos < 512) {
        widx[b * 512 + pos] = o;
        wval[b * 512 + pos] = pv;  // un-boosted value, like ref
      }
    }
  }
  __syncthreads();
  if (tid == 0) wcnt[b] = cnt < 512 ? cnt : 512;
}

// ---------------- k_fc: sequential-k f32 sparse fc1 + kwinners(k=100, >=thr) + f64 fc2 + log_softmax ----------------
__global__ __launch_bounds__(256) void k_fc(const unsigned* __restrict__ Wt2,
                                            const float* __restrict__ WtF,
                                            const float* __restrict__ wval,
                                            const int* __restrict__ widx,
                                            const int* __restrict__ wcnt,
                                            const void* __restrict__ fc1b,
                                            const void* __restrict__ dutyfc,
                                            const void* __restrict__ fc2w,
                                            const void* __restrict__ fc2b,
                                            void* __restrict__ out,
                                            const int* __restrict__ flag) {
  __shared__ float lval[512];
  __shared__ int lidx[512];
  __shared__ float oval[512];
  __shared__ int olist[512];
  __shared__ unsigned hist[256];
  __shared__ unsigned selb, selk;
  __shared__ double lg[10];
  __shared__ double mred[2];
  const int tid = threadIdx.x;
  const int row = blockIdx.x;
  const int isb = *flag;
  const int cnt = wcnt[row];
  for (int i = tid; i < cnt; i += 256) {
    lval[i] = wval[row * 512 + i];
    lidx[i] = widx[row * 512 + i];
  }
  if (tid < 10) lg[tid] = (double)gload(fc2b, tid, isb);
  __syncthreads();

  // sort winners by original k index (counting sort; indices unique)
  for (int i = tid; i < cnt; i += 256) {
    int my = lidx[i];
    int pos = 0;
    for (int j = 0; j < cnt; ++j) pos += (lidx[j] < my) ? 1 : 0;
    olist[pos] = my;
    oval[pos] = lval[i];
  }
  __syncthreads();

  // h: single f32 fmaf chain per unit, ascending k (gemm micro-kernel order;
  // skipped zero terms are exact no-ops). Thread owns units 2t,2t+1,512+2t,513+2t.
  float acc0 = 0.f, acc1 = 0.f, acc2 = 0.f, acc3 = 0.f;
  if (isb) {
    for (int w = 0; w < cnt; ++w) {
      float v = oval[w];
      const unsigned* wr = Wt2 + olist[w] * 512;
      unsigned p0 = wr[tid];
      unsigned p1 = wr[tid + 256];
      acc0 = fmaf(v, __uint_as_float(p0 << 16), acc0);
      acc1 = fmaf(v, __uint_as_float(p0 & 0xFFFF0000u), acc1);
      acc2 = fmaf(v, __uint_as_float(p1 << 16), acc2);
      acc3 = fmaf(v, __uint_as_float(p1 & 0xFFFF0000u), acc3);
    }
  } else {
    for (int w = 0; w < cnt; ++w) {
      float v = oval[w];
      const float* wr = WtF + olist[w] * 1024;
      acc0 = fmaf(v, wr[2 * tid], acc0);
      acc1 = fmaf(v, wr[2 * tid + 1], acc1);
      acc2 = fmaf(v, wr[512 + 2 * tid], acc2);
      acc3 = fmaf(v, wr[513 + 2 * tid], acc3);
    }
  }
  const int u0 = 2 * tid, u1 = 2 * tid + 1, u2 = 512 + 2 * tid, u3 = 513 + 2 * tid;
  float h0 = acc0 + gload(fc1b, u0, isb);
  float h1 = acc1 + gload(fc1b, u1, isb);
  float h2 = acc2 + gload(fc1b, u2, isb);
  float h3 = acc3 + gload(fc1b, u3, isb);
  float bf0 = (float)exp((double)(0.09765625f - gload(dutyfc, u0, isb)));
  float bf1 = (float)exp((double)(0.09765625f - gload(dutyfc, u1, isb)));
  float bf2 = (float)exp((double)(0.09765625f - gload(dutyfc, u2, isb)));
  float bf3 = (float)exp((double)(0.09765625f - gload(dutyfc, u3, isb)));
  unsigned k0 = tokey(h0 * bf0);
  unsigned k1 = tokey(h1 * bf1);
  unsigned k2 = tokey(h2 * bf2);
  unsigned k3 = tokey(h3 * bf3);

  // radix-select: 100th largest of 1024 f32 keys
  unsigned kfix = 0;
  int kk = 100;
  for (int pass = 3; pass >= 0; --pass) {
    const int shift = pass * 8;
    const unsigned himask = (pass == 3) ? 0u : (0xFFFFFFFFu << (shift + 8));
    hist[tid] = 0;
    __syncthreads();
    if (((k0 ^ kfix) & himask) == 0) atomicAdd(&hist[(k0 >> shift) & 255u], 1u);
    if (((k1 ^ kfix) & himask) == 0) atomicAdd(&hist[(k1 >> shift) & 255u], 1u);
    if (((k2 ^ kfix) & himask) == 0) atomicAdd(&hist[(k2 >> shift) & 255u], 1u);
    if (((k3 ^ kfix) & himask) == 0) atomicAdd(&hist[(k3 >> shift) & 255u], 1u);
    __syncthreads();
    unsigned v = hist[tid];
    for (int offs = 1; offs < 256; offs <<= 1) {
      unsigned other = (tid + offs < 256) ? hist[tid + offs] : 0u;
      __syncthreads();
      v += other;
      hist[tid] = v;
      __syncthreads();
    }
    unsigned snext = (tid < 255) ? hist[tid + 1] : 0u;
    if (v >= (unsigned)kk && snext < (unsigned)kk) {
      selb = (unsigned)tid;
      selk = (unsigned)(kk - (int)snext);
    }
    __syncthreads();
    kfix |= selb << shift;
    kk = (int)selk;
    __syncthreads();
  }
  bool kp0 = k0 >= kfix, kp1 = k1 >= kfix, kp2 = k2 >= kfix, kp3 = k3 >= kfix;

  // fc2 on kept units only (f64; post-selection value noise ~1e-7, harmless)
  double part[10];
#pragma unroll
  for (int c = 0; c < 10; ++c) part[c] = 0.0;
  if (kp0) {
#pragma unroll
    for (int c = 0; c < 10; ++c) part[c] = fma((double)h0, (double)gload(fc2w, c * 1024 + u0, isb), part[c]);
  }
  if (kp1) {
#pragma unroll
    for (int c = 0; c < 10; ++c) part[c] = fma((double)h1, (double)gload(fc2w, c * 1024 + u1, isb), part[c]);
  }
  if (kp2) {
#pragma unroll
    for (int c = 0; c < 10; ++c) part[c] = fma((double)h2, (double)gload(fc2w, c * 1024 + u2, isb), part[c]);
  }
  if (kp3) {
#pragma unroll
    for (int c = 0; c < 10; ++c) part[c] = fma((double)h3, (double)gload(fc2w, c * 1024 + u3, isb), part[c]);
  }
#pragma unroll
  for (int c = 0; c < 10; ++c) {
    double p = part[c];
    for (int off = 32; off > 0; off >>= 1) p += __shfl_xor(p, off);
    if ((tid & 63) == 0) atomicAdd(&lg[c], p);
  }
  __syncthreads();
  if (tid == 0) {
    double m = lg[0];
#pragma unroll
    for (int c = 1; c < 10; ++c) m = lg[c] > m ? lg[c] : m;
    double sum = 0.0;
#pragma unroll
    for (int c = 0; c < 10; ++c) sum += exp(lg[c] - m);
    mred[0] = m;
    mred[1] = log(sum);
  }
  __syncthreads();
  if (tid < 10) {
    double o = lg[tid] - mred[0] - mred[1];
    if (isb)
      ((unsigned short*)out)[row * 10 + tid] = f2b((float)o);
    else
      ((float*)out)[row * 10 + tid] = (float)o;
  }
}

// ---------------- launch ----------------
extern "C" void kernel_launch(void* const* d_in, const int* in_sizes, int n_in,
                              void* d_out, int out_size, void* d_ws, size_t ws_size,
                              hipStream_t stream) {
  // ws layout (bytes):
  //   WtF  : 9216*1024*4 = 37,748,736  @ 0           (f32 transposed masked weights)
  //   Wt2  : 9216*512*4  = 18,874,368  @ 37,748,736  (bf16-pair variant)
  //   wval : 4096*512*4  =  8,388,608  @ 56,623,104
  //   widx : 4096*512*4  =  8,388,608  @ 65,011,712
  //   wcnt : 4096*4      =     16,384  @ 73,400,320
  //   flag : 4                         @ 73,416,704
  char* ws = (char*)d_ws;
  float* WtF = (float*)ws;
  unsigned* Wt2 = (unsigned*)(ws + 37748736);
  float* wval = (float*)(ws + 56623104);
  int* widx = (int*)(ws + 65011712);
  int* wcnt = (int*)(ws + 73400320);
  int* flag = (int*)(ws + 73416704);

  k_detect<<<1, 64, 0, stream>>>(d_in[0], flag);
  k_prep<<<dim3(144, 16), 256, 0, stream>>>(d_in[4], d_in[5], Wt2, WtF, flag);
  k_conv<<<4096, 256, 0, stream>>>(d_in[0], d_in[1], d_in[2], d_in[3],
                                   wval, widx, wcnt, flag);
  k_fc<<<4096, 256, 0, stream>>>(Wt2, WtF, wval, widx, wcnt, d_in[6], d_in[7],
                                 d_in[8], d_in[9], d_out, flag);
}

// Round 6
// 656.961 us; speedup vs baseline: 1.3678x; 1.3678x over previous
//
#include <hip/hip_runtime.h>

// ---------------- dtype helpers ----------------
__device__ __forceinline__ float b2f(unsigned short u) {
  return __uint_as_float(((unsigned)u) << 16);
}
__device__ __forceinline__ unsigned short f2b(float f) {
  unsigned u = __float_as_uint(f);
  return (unsigned short)((u + 0x7FFFu + ((u >> 16) & 1u)) >> 16);
}
// load element i of a tensor that is bf16 (isb=1) or fp32 (isb=0)
__device__ __forceinline__ float gload(const void* p, int i, int isb) {
  return isb ? b2f(((const unsigned short*)p)[i]) : ((const float*)p)[i];
}
// monotone bijection float -> uint32 (order-preserving incl. negatives)
__device__ __forceinline__ unsigned tokey(float f) {
  unsigned u = __float_as_uint(f);
  return u ^ (unsigned)(((int)u >> 31) | 0x80000000u);
}

// ---------------- dtype detector (dataset proven fp32; kept for safety) ----------------
__global__ void k_detect(const void* x, int* flag) {
  int tid = threadIdx.x;  // 1 wave
  unsigned short u = ((const unsigned short*)x)[2 * tid];
  int e = (u >> 7) & 0xFF;
  bool sane = (e >= 100 && e <= 140);
  unsigned long long m = __ballot(sane);
  if (tid == 0) *flag = (__popcll(m) >= 40) ? 1 : 0;
}

// ---------------- k_prep: WtF[i][u] = fc1_w[u][i] * (mask<0.5), f32 transposed ----------------
__global__ __launch_bounds__(256) void k_prep(const void* __restrict__ fc1w,
                                              const void* __restrict__ mraw,
                                              float* __restrict__ WtF,
                                              const int* __restrict__ flag) {
  __shared__ float tile[64][65];
  const int isb = *flag;
  const int i0 = blockIdx.x * 64;  // K index (9216)
  const int u0 = blockIdx.y * 64;  // unit index (1024)
  const int tx = threadIdx.x & 63, ty = threadIdx.x >> 6;
  for (int uu = ty; uu < 64; uu += 4) {
    int gi = (u0 + uu) * 9216 + i0 + tx;
    float wv = gload(fc1w, gi, isb);
    float mv = gload(mraw, gi, isb);
    tile[uu][tx] = (mv < 0.5f) ? wv : 0.0f;
  }
  __syncthreads();
  for (int ii = ty; ii < 64; ii += 4)
    WtF[(i0 + ii) * 1024 + u0 + tx] = tile[tx][ii];
}

// ---------------- k_conv: f32 conv5x5 (Eigen kh-fastest order), bias, maxpool2, kwinners ----------------
// Emits winners SORTED by flat index (per-thread ranges are contiguous ascending).
__global__ __launch_bounds__(256) void k_conv(const void* __restrict__ x,
                                              const void* __restrict__ c1w_g,
                                              const void* __restrict__ c1b_g,
                                              const void* __restrict__ duty_g,
                                              int2* __restrict__ wpair,
                                              int* __restrict__ wcnt,
                                              const int* __restrict__ flag) {
  __shared__ __align__(16) float img[784];
  __shared__ float cw[1600];
  __shared__ float cb[64], bcs[64];
  __shared__ __align__(16) float pooled[9216];
  __shared__ unsigned hist[256];
  __shared__ unsigned selb, selk;
  const int tid = threadIdx.x;
  const int b = blockIdx.x;
  const int isb = *flag;

  for (int i = tid; i < 784; i += 256) img[i] = gload(x, b * 784 + i, isb);
  for (int i = tid; i < 1600; i += 256) cw[i] = gload(c1w_g, i, isb);
  if (tid < 64) {
    cb[tid] = gload(c1b_g, tid, isb);
    float arg = (float)(400.0 / 9216.0) - gload(duty_g, tid, isb);
    bcs[tid] = (float)exp((double)arg);
  }
  __syncthreads();

  // 1536 tasks = 64 ch x 12 pooled rows x 2 halves; 6 per thread.
  // Single sequential fmaf chain per conv cell in k = kw*5 + kh order
  // (kh fastest -- Eigen patch linearization) => bit-exact vs reference.
  for (int s = 0; s < 6; ++s) {
    int t = tid + (s << 8);
    int c = t / 24;
    int sub = t - c * 24;
    int ph = sub >> 1;
    int half = sub & 1;
    float w[25];
#pragma unroll
    for (int i = 0; i < 25; ++i) w[i] = cw[c * 25 + i];
    float R[6][16];
#pragma unroll
    for (int rr = 0; rr < 6; ++rr) {
      int row = 2 * ph + rr;
#pragma unroll
      for (int q = 0; q < 4; ++q)
        ((float4*)&R[rr][0])[q] = ((const float4*)img)[row * 7 + half * 3 + q];
    }
    float a0[12], a1[12];
#pragma unroll
    for (int j = 0; j < 12; ++j) { a0[j] = 0.f; a1[j] = 0.f; }
#pragma unroll
    for (int kj = 0; kj < 5; ++kj) {       // kw OUTER
#pragma unroll
      for (int kr = 0; kr < 5; ++kr) {     // kh INNER (fastest)
        float wk = w[kr * 5 + kj];
#pragma unroll
        for (int j = 0; j < 12; ++j) {
          a0[j] = fmaf(R[kr][j + kj], wk, a0[j]);
          a1[j] = fmaf(R[kr + 1][j + kj], wk, a1[j]);
        }
      }
    }
    float bias = cb[c];
    int obase = c * 144 + ph * 12 + half * 6;
#pragma unroll
    for (int q = 0; q < 6; ++q) {
      float m = fmaxf(fmaxf(a0[2 * q], a0[2 * q + 1]),
                      fmaxf(a1[2 * q], a1[2 * q + 1]));
      pooled[obase + q] = m + bias;
    }
  }
  __syncthreads();

  // radix-select the 400th-largest f32 boosted key (exact top_k threshold)
  unsigned kfix = 0;
  int kk = 400;
  for (int pass = 3; pass >= 0; --pass) {
    const int shift = pass * 8;
    const unsigned himask = (pass == 3) ? 0u : (0xFFFFFFFFu << (shift + 8));
    hist[tid] = 0;
    __syncthreads();
    for (int e = 0; e < 9; ++e) {
      float4 pv = ((float4*)pooled)[tid * 9 + e];
#pragma unroll
      for (int q = 0; q < 4; ++q) {
        int o = tid * 36 + e * 4 + q;
        unsigned key = tokey(((float*)&pv)[q] * bcs[o / 144]);
        if (((key ^ kfix) & himask) == 0)
          atomicAdd(&hist[(key >> shift) & 255u], 1u);
      }
    }
    __syncthreads();
    unsigned v = hist[tid];
    for (int offs = 1; offs < 256; offs <<= 1) {
      unsigned other = (tid + offs < 256) ? hist[tid + offs] : 0u;
      __syncthreads();
      v += other;
      hist[tid] = v;
      __syncthreads();
    }
    unsigned snext = (tid < 255) ? hist[tid + 1] : 0u;
    if (v >= (unsigned)kk && snext < (unsigned)kk) {
      selb = (unsigned)tid;
      selk = (unsigned)(kk - (int)snext);
    }
    __syncthreads();
    kfix |= selb << shift;
    kk = (int)selk;
    __syncthreads();
  }

  // sorted compaction: per-thread count -> block scan -> ordered write.
  // keep ALL with key >= kfix (== boosted >= thr bitwise, ties kept like ref)
  int mycnt = 0;
#pragma unroll
  for (int e = 0; e < 36; ++e) {
    int o = tid * 36 + e;
    if (tokey(pooled[o] * bcs[o / 144]) >= kfix) ++mycnt;
  }
  hist[tid] = (unsigned)mycnt;
  __syncthreads();
  unsigned v2 = hist[tid];
  for (int offs = 1; offs < 256; offs <<= 1) {
    unsigned other = (tid >= offs) ? hist[tid - offs] : 0u;
    __syncthreads();
    v2 += other;
    hist[tid] = v2;
    __syncthreads();
  }
  int pos = (int)v2 - mycnt;  // exclusive prefix
  for (int e = 0; e < 36; ++e) {
    int o = tid * 36 + e;
    float pv = pooled[o];
    if (tokey(pv * bcs[o / 144]) >= kfix) {
      if (pos < 512) wpair[b * 512 + pos] = make_int2(__float_as_int(pv), o);
      ++pos;
    }
  }
  if (tid == 255) wcnt[b] = (int)(v2 < 512u ? v2 : 512u);
}

// ---------------- k_fc1: XCD-sliced sparse fc1 gather ----------------
// slice = blockIdx.x & 7 -> consecutive blocks round-robin across the 8 XCDs,
// so each XCD's L2 only sees its 128-unit column slice of WtF (4.7 MB ~ L2).
// Thread owns ONE unit: single f32 fmaf chain over winners ascending-k ->
// bit-identical h to the previously passing kernel.
__global__ __launch_bounds__(128) void k_fc1(const float* __restrict__ WtF,
                                             const int2* __restrict__ wpair,
                                             const int* __restrict__ wcnt,
                                             const void* __restrict__ fc1b,
                                             float* __restrict__ h,
                                             const int* __restrict__ flag) {
  __shared__ float sval[512];
  __shared__ int sidx[512];
  const int tid = threadIdx.x;
  const int img = blockIdx.x >> 3;
  const int slice = blockIdx.x & 7;
  const int isb = *flag;
  const int cnt = wcnt[img];
  for (int i = tid; i < cnt; i += 128) {
    int2 p = wpair[img * 512 + i];
    sval[i] = __int_as_float(p.x);
    sidx[i] = p.y;
  }
  __syncthreads();
  const int u = (slice << 7) | tid;
  const float* W = WtF + u;
  float acc = 0.f;
  for (int w = 0; w < cnt; ++w)
    acc = fmaf(sval[w], W[sidx[w] * 1024], acc);
  h[img * 1024 + u] = acc + gload(fc1b, u, isb);
}

// ---------------- k_sel: kwinners(k=100, >=thr) + f64 fc2 + log_softmax ----------------
__global__ __launch_bounds__(256) void k_sel(const float* __restrict__ h,
                                             const void* __restrict__ dutyfc,
                                             const void* __restrict__ fc2w,
                                             const void* __restrict__ fc2b,
                                             void* __restrict__ out,
                                             const int* __restrict__ flag) {
  __shared__ unsigned hist[256];
  __shared__ unsigned selb, selk;
  __shared__ double lg[10];
  __shared__ double mred[2];
  const int tid = threadIdx.x;
  const int row = blockIdx.x;
  const int isb = *flag;
  if (tid < 10) lg[tid] = (double)gload(fc2b, tid, isb);
  __syncthreads();

  const int u0 = 2 * tid, u1 = 2 * tid + 1, u2 = 512 + 2 * tid, u3 = 513 + 2 * tid;
  float2 hlo = ((const float2*)(h + row * 1024))[tid];
  float2 hhi = ((const float2*)(h + row * 1024 + 512))[tid];
  float h0 = hlo.x, h1 = hlo.y, h2 = hhi.x, h3 = hhi.y;
  float bf0 = (float)exp((double)(0.09765625f - gload(dutyfc, u0, isb)));
  float bf1 = (float)exp((double)(0.09765625f - gload(dutyfc, u1, isb)));
  float bf2 = (float)exp((double)(0.09765625f - gload(dutyfc, u2, isb)));
  float bf3 = (float)exp((double)(0.09765625f - gload(dutyfc, u3, isb)));
  unsigned k0 = tokey(h0 * bf0);
  unsigned k1 = tokey(h1 * bf1);
  unsigned k2 = tokey(h2 * bf2);
  unsigned k3 = tokey(h3 * bf3);

  // radix-select: 100th largest of 1024 f32 keys
  unsigned kfix = 0;
  int kk = 100;
  for (int pass = 3; pass >= 0; --pass) {
    const int shift = pass * 8;
    const unsigned himask = (pass == 3) ? 0u : (0xFFFFFFFFu << (shift + 8));
    hist[tid] = 0;
    __syncthreads();
    if (((k0 ^ kfix) & himask) == 0) atomicAdd(&hist[(k0 >> shift) & 255u], 1u);
    if (((k1 ^ kfix) & himask) == 0) atomicAdd(&hist[(k1 >> shift) & 255u], 1u);
    if (((k2 ^ kfix) & himask) == 0) atomicAdd(&hist[(k2 >> shift) & 255u], 1u);
    if (((k3 ^ kfix) & himask) == 0) atomicAdd(&hist[(k3 >> shift) & 255u], 1u);
    __syncthreads();
    unsigned v = hist[tid];
    for (int offs = 1; offs < 256; offs <<= 1) {
      unsigned other = (tid + offs < 256) ? hist[tid + offs] : 0u;
      __syncthreads();
      v += other;
      hist[tid] = v;
      __syncthreads();
    }
    unsigned snext = (tid < 255) ? hist[tid + 1] : 0u;
    if (v >= (unsigned)kk && snext < (unsigned)kk) {
      selb = (unsigned)tid;
      selk = (unsigned)(kk - (int)snext);
    }
    __syncthreads();
    kfix |= selb << shift;
    kk = (int)selk;
    __syncthreads();
  }
  bool kp0 = k0 >= kfix, kp1 = k1 >= kfix, kp2 = k2 >= kfix, kp3 = k3 >= kfix;

  // fc2 on kept units only (f64), wave-reduce, LDS-atomic combine
  double part[10];
#pragma unroll
  for (int c = 0; c < 10; ++c) part[c] = 0.0;
  if (kp0) {
#pragma unroll
    for (int c = 0; c < 10; ++c) part[c] = fma((double)h0, (double)gload(fc2w, c * 1024 + u0, isb), part[c]);
  }
  if (kp1) {
#pragma unroll
    for (int c = 0; c < 10; ++c) part[c] = fma((double)h1, (double)gload(fc2w, c * 1024 + u1, isb), part[c]);
  }
  if (kp2) {
#pragma unroll
    for (int c = 0; c < 10; ++c) part[c] = fma((double)h2, (double)gload(fc2w, c * 1024 + u2, isb), part[c]);
  }
  if (kp3) {
#pragma unroll
    for (int c = 0; c < 10; ++c) part[c] = fma((double)h3, (double)gload(fc2w, c * 1024 + u3, isb), part[c]);
  }
#pragma unroll
  for (int c = 0; c < 10; ++c) {
    double p = part[c];
    for (int off = 32; off > 0; off >>= 1) p += __shfl_xor(p, off);
    if ((tid & 63) == 0) atomicAdd(&lg[c], p);
  }
  __syncthreads();
  if (tid == 0) {
    double m = lg[0];
#pragma unroll
    for (int c = 1; c < 10; ++c) m = lg[c] > m ? lg[c] : m;
    double sum = 0.0;
#pragma unroll
    for (int c = 0; c < 10; ++c) sum += exp(lg[c] - m);
    mred[0] = m;
    mred[1] = log(sum);
  }
  __syncthreads();
  if (tid < 10) {
    double o = lg[tid] - mred[0] - mred[1];
    if (isb)
      ((unsigned short*)out)[row * 10 + tid] = f2b((float)o);
    else
      ((float*)out)[row * 10 + tid] = (float)o;
  }
}

// ---------------- launch ----------------
extern "C" void kernel_launch(void* const* d_in, const int* in_sizes, int n_in,
                              void* d_out, int out_size, void* d_ws, size_t ws_size,
                              hipStream_t stream) {
  // ws layout (bytes):
  //   WtF   : 9216*1024*4 = 37,748,736  @ 0
  //   wpair : 4096*512*8  = 16,777,216  @ 37,748,736
  //   wcnt  : 4096*4      =     16,384  @ 54,525,952
  //   h     : 4096*1024*4 = 16,777,216  @ 54,542,336
  //   flag  : 4                         @ 71,319,552
  char* ws = (char*)d_ws;
  float* WtF = (float*)ws;
  int2* wpair = (int2*)(ws + 37748736);
  int* wcnt = (int*)(ws + 54525952);
  float* h = (float*)(ws + 54542336);
  int* flag = (int*)(ws + 71319552);

  k_detect<<<1, 64, 0, stream>>>(d_in[0], flag);
  k_prep<<<dim3(144, 16), 256, 0, stream>>>(d_in[4], d_in[5], WtF, flag);
  k_conv<<<4096, 256, 0, stream>>>(d_in[0], d_in[1], d_in[2], d_in[3],
                                   wpair, wcnt, flag);
  k_fc1<<<4096 * 8, 128, 0, stream>>>(WtF, wpair, wcnt, d_in[6], h, flag);
  k_sel<<<4096, 256, 0, stream>>>(h, d_in[7], d_in[8], d_in[9], d_out, flag);
}